// Round 3
// baseline (832.206 us; speedup 1.0000x reference)
//
#include <hip/hip_runtime.h>
#include <stdint.h>

typedef unsigned int u32;
typedef unsigned short u16;
typedef short short8 __attribute__((ext_vector_type(8)));
typedef float f32x4 __attribute__((ext_vector_type(4)));

// ---------- problem constants ----------
#define NTOT  4300992
#define JRANK 2150496u

#define SO1 0
#define SO2 1728
#define SO3 38592
#define SO4 4232896
#define SO5 4298432

// params indices
#define P_BIN    0
#define P_JP     1
#define P_TBITS  3
#define P_R      4
#define P_TIECNT 5
#define P_CUT    6

// ---------- workspace layout (bytes) ----------
#define WS_HIST1      0u          // 4096 u32
#define WS_HIST2      16384u      // 524288 u32
#define WS_COARSE     2113536u    // 1024 u32
#define WS_PARAMS     2117632u    // 64 u32
#define WS_ZERO_BYTES 2117888u
#define WS_TIES       2117888u    // 8192 u32
#define WS_WM         4194304u    // NTOT f32
#define WS_ACTA       33554432u   // 512*64*1024 u32 (bf16 hi|lo packed)
#define WS_ACTBH      167772160u  // 512*16384 u16
#define WS_ACTBL      184549376u  // 512*16384 u16
#define WS_PART       201326592u  // 8*512*256 f32
#define WS_ACTC       205520896u  // 512*256 f32
#define WS_ACTD       206045184u  // 512*256 f32

#define TIE_CAP 8192

// ---------- helpers ----------
__device__ __forceinline__ float load_seg(int i, const float* a1, const float* a2,
                                          const float* a3, const float* a4, const float* a5) {
  if (i < SO2) return a1[i];
  if (i < SO3) return a2[i - SO2];
  if (i < SO4) return a3[i - SO3];
  if (i < SO5) return a4[i - SO4];
  return a5[i - SO5];
}

__device__ __forceinline__ u32 absbits(float v) {
  return __float_as_uint(v) & 0x7FFFFFFFu;
}

// round-to-nearest-even fp32 -> bf16 (bits)
__device__ __forceinline__ u16 bf16rne(float f) {
  u32 u = __float_as_uint(f);
  u32 r = (u + 0x7FFFu + ((u >> 16) & 1u)) >> 16;
  return (u16)r;
}
__device__ __forceinline__ float bf16tof(u16 h) {
  return __uint_as_float(((u32)h) << 16);
}

// ---------- selection: level-1 histogram (bits [30:19], 4096 bins) ----------
__global__ __launch_bounds__(256) void k_hist1(const float* s1, const float* s2, const float* s3,
                                               const float* s4, const float* s5, u32* hist1) {
  __shared__ u32 h[4096];
  for (int i = threadIdx.x; i < 4096; i += 256) h[i] = 0;
  __syncthreads();
  int stride = gridDim.x * blockDim.x;
  for (int i = blockIdx.x * 256 + threadIdx.x; i < NTOT; i += stride) {
    u32 b = absbits(load_seg(i, s1, s2, s3, s4, s5)) >> 19;
    atomicAdd(&h[b], 1u);
  }
  __syncthreads();
  for (int i = threadIdx.x; i < 4096; i += 256) {
    u32 c = h[i];
    if (c) atomicAdd(&hist1[i], c);
  }
}

// ---------- scan level-1: find bin containing rank JRANK ----------
__global__ __launch_bounds__(1024) void k_scan1(const u32* hist1, u32* params) {
  __shared__ u32 sc[1024];
  int t = threadIdx.x;
  u32 loc[4];
  u32 own = 0;
#pragma unroll
  for (int i = 0; i < 4; i++) { loc[i] = hist1[t * 4 + i]; own += loc[i]; }
  sc[t] = own; __syncthreads();
  for (int off = 1; off < 1024; off <<= 1) {
    u32 add = (t >= off) ? sc[t - off] : 0;
    __syncthreads();
    sc[t] += add;
    __syncthreads();
  }
  u32 incl = sc[t], excl = incl - own;
  if (JRANK >= excl && JRANK < incl) {
    u32 run = excl;
#pragma unroll
    for (int i = 0; i < 4; i++) {
      if (JRANK < run + loc[i]) { params[P_BIN] = (u32)(t * 4 + i); params[P_JP] = JRANK - run; break; }
      run += loc[i];
    }
  }
}

// ---------- level-2 histogram (bits [18:0] of elements in selected bin) ----------
__global__ __launch_bounds__(256) void k_hist2(const float* s1, const float* s2, const float* s3,
                                               const float* s4, const float* s5,
                                               const u32* params, u32* hist2) {
  u32 bsel = params[P_BIN];
  int stride = gridDim.x * blockDim.x;
  for (int i = blockIdx.x * 256 + threadIdx.x; i < NTOT; i += stride) {
    u32 b = absbits(load_seg(i, s1, s2, s3, s4, s5));
    if ((b >> 19) == bsel) atomicAdd(&hist2[b & 0x7FFFFu], 1u);
  }
}

// ---------- coarse reduction of hist2 (1024 segments of 512) ----------
__global__ __launch_bounds__(256) void k_coarse(const u32* hist2, u32* coarse) {
  __shared__ u32 red[256];
  int blk = blockIdx.x;
  u32 s = hist2[blk * 512 + threadIdx.x] + hist2[blk * 512 + 256 + threadIdx.x];
  red[threadIdx.x] = s; __syncthreads();
  for (int off = 128; off > 0; off >>= 1) {
    if (threadIdx.x < off) red[threadIdx.x] += red[threadIdx.x + off];
    __syncthreads();
  }
  if (threadIdx.x == 0) coarse[blk] = red[0];
}

// ---------- scan level-2: exact threshold bits + within-tie rank r ----------
__global__ __launch_bounds__(1024) void k_scan2(const u32* hist2, const u32* coarse, u32* params) {
  __shared__ u32 sc[1024];
  __shared__ u32 s_seg, s_base;
  int t = threadIdx.x;
  u32 jp = params[P_JP];
  u32 own = coarse[t];
  sc[t] = own; __syncthreads();
  for (int off = 1; off < 1024; off <<= 1) {
    u32 add = (t >= off) ? sc[t - off] : 0;
    __syncthreads();
    sc[t] += add;
    __syncthreads();
  }
  u32 incl = sc[t], excl = incl - own;
  if (jp >= excl && jp < incl) { s_seg = (u32)t; s_base = excl; }
  __syncthreads();
  u32 seg = s_seg, base = s_base, tgt = jp - base;
  u32 own2 = (t < 512) ? hist2[seg * 512 + t] : 0;
  __syncthreads();
  sc[t] = own2; __syncthreads();
  for (int off = 1; off < 1024; off <<= 1) {
    u32 add = (t >= off) ? sc[t - off] : 0;
    __syncthreads();
    sc[t] += add;
    __syncthreads();
  }
  u32 incl2 = sc[t], excl2 = incl2 - own2;
  if (t < 512 && tgt >= excl2 && tgt < incl2) {
    u32 b = params[P_BIN];
    params[P_TBITS] = (b << 19) | (seg * 512 + (u32)t);
    params[P_R] = tgt - excl2;
  }
}

// ---------- collect flat indices tied with threshold value ----------
__global__ __launch_bounds__(256) void k_tie(const float* s1, const float* s2, const float* s3,
                                             const float* s4, const float* s5,
                                             u32* params, u32* ties) {
  u32 tb = params[P_TBITS];
  int stride = gridDim.x * blockDim.x;
  for (int i = blockIdx.x * 256 + threadIdx.x; i < NTOT; i += stride) {
    if (absbits(load_seg(i, s1, s2, s3, s4, s5)) == tb) {
      u32 pos = atomicAdd(&params[P_TIECNT], 1u);
      if (pos < TIE_CAP) ties[pos] = (u32)i;
    }
  }
}

// ---------- flat-index cutoff among tied elements (stable-sort semantics) ----------
__global__ void k_cut(u32* params, const u32* ties) {
  if (threadIdx.x != 0 || blockIdx.x != 0) return;
  u32 m = params[P_TIECNT]; if (m > TIE_CAP) m = TIE_CAP;
  u32 r = params[P_R];
  u32 cut;
  if (r == 0) cut = 0u;
  else if (r >= m) cut = 0xFFFFFFFFu;
  else {
    long long last = -1;
    for (u32 s = 0; s < r; s++) {
      u32 cur = 0xFFFFFFFFu;
      for (u32 k = 0; k < m; k++) {
        u32 v = ties[k];
        if ((long long)v > last && v < cur) cur = v;
      }
      last = (long long)cur;
    }
    cut = (u32)(last + 1);
  }
  params[P_CUT] = cut;
}

// ---------- apply mask: wm[i] = keep ? w[i] : 0 ----------
__global__ __launch_bounds__(256) void k_mask(const float* s1, const float* s2, const float* s3,
                                              const float* s4, const float* s5,
                                              const float* w1, const float* w2, const float* w3,
                                              const float* w4, const float* w5,
                                              const u32* params, float* wm) {
  u32 tb = params[P_TBITS];
  u32 cut = params[P_CUT];
  int stride = gridDim.x * blockDim.x;
  for (int i = blockIdx.x * 256 + threadIdx.x; i < NTOT; i += stride) {
    u32 b = absbits(load_seg(i, s1, s2, s3, s4, s5));
    bool keep = (b > tb) || (b == tb && (u32)i >= cut);
    wm[i] = keep ? load_seg(i, w1, w2, w3, w4, w5) : 0.0f;
  }
}

// ---------- conv1: [512,3,32,32] -> relu -> bf16 hi/lo packed u32 [512,64,32,32] ----------
__global__ __launch_bounds__(256) void k_conv1(const float* __restrict__ x,
                                               const float* __restrict__ wm1,
                                               u32* __restrict__ actA2) {
  __shared__ float xs[3][34][35];
  __shared__ float ws[64][27];
  int b = blockIdx.x;
  int tid = threadIdx.x;
  for (int i = tid; i < 3 * 34 * 35; i += 256) ((float*)xs)[i] = 0.0f;
  for (int i = tid; i < 1728; i += 256) ((float*)ws)[i] = wm1[i];
  __syncthreads();
  const float4* xp = (const float4*)(x + (size_t)b * 3072);
  for (int i = tid; i < 768; i += 256) {
    float4 v = xp[i];
    int c = i >> 8, p = i & 255, r = p >> 3, c4 = p & 7;
    float* dst = &xs[c][r + 1][c4 * 4 + 1];
    dst[0] = v.x; dst[1] = v.y; dst[2] = v.z; dst[3] = v.w;
  }
  __syncthreads();
  int och = tid >> 7, y = (tid >> 2) & 31, xg = tid & 3, x0 = xg * 8;
  for (int q = 0; q < 8; q++) {
    int ocb = och * 32 + q * 4;
    float acc[4][8];
#pragma unroll
    for (int o = 0; o < 4; o++)
#pragma unroll
      for (int p = 0; p < 8; p++) acc[o][p] = 0.0f;
    for (int c = 0; c < 3; c++) {
      float in[3][10];
#pragma unroll
      for (int dy = 0; dy < 3; dy++)
#pragma unroll
        for (int d = 0; d < 10; d++) in[dy][d] = xs[c][y + dy][x0 + d];
#pragma unroll
      for (int o = 0; o < 4; o++) {
#pragma unroll
        for (int ky = 0; ky < 3; ky++)
#pragma unroll
          for (int kx = 0; kx < 3; kx++) {
            float wv = ws[ocb + o][c * 9 + ky * 3 + kx];
#pragma unroll
            for (int px = 0; px < 8; px++) acc[o][px] += wv * in[ky][px + kx];
          }
      }
    }
#pragma unroll
    for (int o = 0; o < 4; o++) {
      u32 w8[8];
#pragma unroll
      for (int px = 0; px < 8; px++) {
        float v = fmaxf(acc[o][px], 0.f);
        u16 h = bf16rne(v);
        u16 lo = bf16rne(v - bf16tof(h));
        w8[px] = (u32)h | ((u32)lo << 16);
      }
      uint4* dst = (uint4*)(actA2 + (((size_t)(b * 64 + ocb + o)) << 10) + (y << 5) + x0);
      dst[0] = make_uint4(w8[0], w8[1], w8[2], w8[3]);
      dst[1] = make_uint4(w8[4], w8[5], w8[6], w8[7]);
    }
  }
}

// ---------- conv2 (MFMA bf16 split-3) + relu + maxpool2x2 ----------
// grid: 1024 = img*2 oc-halves. band = 4 output rows. LDS ~126 KB.
__global__ __launch_bounds__(256, 1) void k_conv2(const u32* __restrict__ actA2,
                                                  const float* __restrict__ wm2,
                                                  u16* __restrict__ actBhi,
                                                  u16* __restrict__ actBlo) {
  __shared__ __align__(16) u16 xh[6 * 34 * 64];
  __shared__ __align__(16) u16 xl[6 * 34 * 64];
  __shared__ __align__(16) u16 wh[9 * 32 * 64];
  __shared__ __align__(16) u16 wl[9 * 32 * 64];
  int blk = blockIdx.x;
  int img = blk >> 1, oc0 = (blk & 1) * 32;
  int tid = threadIdx.x;

  // stage masked weights once: wt[s][ocl 0..31][ic 0..63], XOR-swizzled in ic-bytes
  for (int i = tid; i < 9 * 32 * 64; i += 256) {
    int row = i >> 6;              // s*32 + ocl
    int ocl = row & 31, ic = i & 63, s = row >> 5;
    float v = wm2[(size_t)(oc0 + ocl) * 576 + ic * 9 + s];
    u16 h = bf16rne(v);
    u16 lo = bf16rne(v - bf16tof(h));
    int e = ((2 * ic) ^ ((row & 7) << 4)) >> 1;
    wh[row * 64 + e] = h;
    wl[row * 64 + e] = lo;
  }

  const u32* src = actA2 + (size_t)img * 65536;  // 64 ic * 1024
  int wv = tid >> 6, l = tid & 63;
  int pr = wv & 1, xb = wv >> 1;
  int ln15 = l & 15, lh = l >> 4;
  const f32x4 vzero = {0.f, 0.f, 0.f, 0.f};

  for (int band = 0; band < 8; band++) {
    int r0 = band * 4;
    __syncthreads();
    // stage input rows r0-1 .. r0+4 (6 rows, zero-padded), hi/lo split
    for (int i = tid; i < 6 * 34 * 64; i += 256) {
      int row = i >> 6, ic = i & 63;
      int yloc = row / 34;
      int xidx = row - yloc * 34;
      int iny = r0 - 1 + yloc, inx = xidx - 1;
      u32 v = 0;
      if (iny >= 0 && iny < 32 && inx >= 0 && inx < 32)
        v = src[ic * 1024 + iny * 32 + inx];
      int e = ((2 * ic) ^ ((row & 7) << 4)) >> 1;
      xh[row * 64 + e] = (u16)(v & 0xFFFFu);
      xl[row * 64 + e] = (u16)(v >> 16);
    }
    __syncthreads();

    f32x4 acc[2][2];
#pragma unroll
    for (int mi = 0; mi < 2; mi++)
#pragma unroll
      for (int t = 0; t < 2; t++) acc[mi][t] = vzero;

#pragma unroll
    for (int ky = 0; ky < 3; ky++) {
#pragma unroll
      for (int kx = 0; kx < 3; kx++) {
        int s = 3 * ky + kx;
#pragma unroll
        for (int c = 0; c < 2; c++) {
          int bb = 64 * c + lh * 16;   // byte offset of fragment within 128-B ic-row
          int rb0 = s * 32 + ln15;
          int rb1 = rb0 + 16;
          short8 bh0 = *(const short8*)&wh[rb0 * 64 + ((bb ^ ((rb0 & 7) << 4)) >> 1)];
          short8 bl0 = *(const short8*)&wl[rb0 * 64 + ((bb ^ ((rb0 & 7) << 4)) >> 1)];
          short8 bh1 = *(const short8*)&wh[rb1 * 64 + ((bb ^ ((rb1 & 7) << 4)) >> 1)];
          short8 bl1 = *(const short8*)&wl[rb1 * 64 + ((bb ^ ((rb1 & 7) << 4)) >> 1)];
#pragma unroll
          for (int mi = 0; mi < 2; mi++) {
            int ra = (2 * pr + mi + ky) * 34 + xb * 16 + ln15 + kx;
            short8 ah = *(const short8*)&xh[ra * 64 + ((bb ^ ((ra & 7) << 4)) >> 1)];
            short8 al = *(const short8*)&xl[ra * 64 + ((bb ^ ((ra & 7) << 4)) >> 1)];
            acc[mi][0] = __builtin_amdgcn_mfma_f32_16x16x32_bf16(ah, bh0, acc[mi][0], 0, 0, 0);
            acc[mi][0] = __builtin_amdgcn_mfma_f32_16x16x32_bf16(ah, bl0, acc[mi][0], 0, 0, 0);
            acc[mi][0] = __builtin_amdgcn_mfma_f32_16x16x32_bf16(al, bh0, acc[mi][0], 0, 0, 0);
            acc[mi][1] = __builtin_amdgcn_mfma_f32_16x16x32_bf16(ah, bh1, acc[mi][1], 0, 0, 0);
            acc[mi][1] = __builtin_amdgcn_mfma_f32_16x16x32_bf16(ah, bl1, acc[mi][1], 0, 0, 0);
            acc[mi][1] = __builtin_amdgcn_mfma_f32_16x16x32_bf16(al, bh1, acc[mi][1], 0, 0, 0);
          }
        }
      }
    }

    // epilogue: maxpool 2x2 + relu + bf16 hi/lo store
    // wave covers conv rows r0+2pr, r0+2pr+1  -> pooled row band*2+pr
    int py = band * 2 + pr;
#pragma unroll
    for (int tau = 0; tau < 2; tau++) {
      int oc = oc0 + tau * 16 + ln15;
      size_t obase = ((size_t)img * 64 + oc) * 256 + py * 16;
#pragma unroll
      for (int u = 0; u < 2; u++) {
        int g = 2 * u;
        float a = fmaxf(fmaxf(acc[0][tau][g], acc[0][tau][g + 1]),
                        fmaxf(acc[1][tau][g], acc[1][tau][g + 1]));
        a = fmaxf(a, 0.0f);
        u16 h = bf16rne(a);
        u16 lo = bf16rne(a - bf16tof(h));
        int px = xb * 8 + lh * 2 + u;
        actBhi[obase + px] = h;
        actBlo[obase + px] = lo;
      }
    }
  }
}

// ---------- fc1 (MFMA bf16 split-3): [512,16384] x [256,16384]^T, K-split 8 ----------
__global__ __launch_bounds__(256) void k_fc1(const u16* __restrict__ Ahi,
                                             const u16* __restrict__ Alo,
                                             const float* __restrict__ f1m,
                                             float* __restrict__ part) {
  __shared__ __align__(16) u16 Ash[64 * 40];
  __shared__ __align__(16) u16 Asl[64 * 40];
  __shared__ __align__(16) u16 Bsh[64 * 40];
  __shared__ __align__(16) u16 Bsl[64 * 40];
  int blk = blockIdx.x;
  int ks = blk >> 5, ms = (blk >> 2) & 7, ns = blk & 3;
  int m0 = ms * 64, n0 = ns * 64, kbase = ks * 2048;
  int tid = threadIdx.x;
  int wv = tid >> 6, l = tid & 63, ln15 = l & 15, lh = l >> 4;
  const f32x4 vzero = {0.f, 0.f, 0.f, 0.f};
  f32x4 acc[4];
#pragma unroll
  for (int i = 0; i < 4; i++) acc[i] = vzero;

  for (int step = 0; step < 64; step++) {
    int k0 = kbase + step * 32;
    __syncthreads();
    for (int i = tid; i < 2048; i += 256) {
      int m = i >> 5, kk = i & 31;
      size_t ga = (size_t)(m0 + m) * 16384 + k0 + kk;
      Ash[m * 40 + kk] = Ahi[ga];
      Asl[m * 40 + kk] = Alo[ga];
      float v = f1m[(size_t)(n0 + m) * 16384 + k0 + kk];
      u16 h = bf16rne(v);
      Bsh[m * 40 + kk] = h;
      Bsl[m * 40 + kk] = bf16rne(v - bf16tof(h));
    }
    __syncthreads();
    int rb = wv * 16 + ln15;
    short8 bh = *(const short8*)&Bsh[rb * 40 + lh * 8];
    short8 bl = *(const short8*)&Bsl[rb * 40 + lh * 8];
#pragma unroll
    for (int mu = 0; mu < 4; mu++) {
      int ra = mu * 16 + ln15;
      short8 ah = *(const short8*)&Ash[ra * 40 + lh * 8];
      short8 al = *(const short8*)&Asl[ra * 40 + lh * 8];
      acc[mu] = __builtin_amdgcn_mfma_f32_16x16x32_bf16(ah, bh, acc[mu], 0, 0, 0);
      acc[mu] = __builtin_amdgcn_mfma_f32_16x16x32_bf16(ah, bl, acc[mu], 0, 0, 0);
      acc[mu] = __builtin_amdgcn_mfma_f32_16x16x32_bf16(al, bh, acc[mu], 0, 0, 0);
    }
  }
  float* dst = part + (size_t)ks * 131072;
#pragma unroll
  for (int mu = 0; mu < 4; mu++) {
#pragma unroll
    for (int g = 0; g < 4; g++) {
      int m = m0 + mu * 16 + lh * 4 + g;
      dst[(size_t)m * 256 + n0 + wv * 16 + ln15] = acc[mu][g];
    }
  }
}

// ---------- fc1 finalize: sum 8 partials + relu ----------
__global__ __launch_bounds__(256) void k_fc1fin(const float* __restrict__ part,
                                                float* __restrict__ actC) {
  int i = blockIdx.x * 256 + threadIdx.x;  // 131072 total
  float s = 0.0f;
#pragma unroll
  for (int ks = 0; ks < 8; ks++) s += part[(size_t)ks * 131072 + i];
  actC[i] = fmaxf(s, 0.0f);
}

// ---------- fc2: [512,256] x [256,256]^T + relu ----------
__global__ __launch_bounds__(256) void k_fc2(const float* __restrict__ actC,
                                             const float* __restrict__ f2m,
                                             float* __restrict__ actD) {
  __shared__ float c1[256];
  int b = blockIdx.x, tid = threadIdx.x;
  c1[tid] = actC[(size_t)b * 256 + tid];
  __syncthreads();
  const float4* wrow = (const float4*)(f2m + (size_t)tid * 256);
  float acc = 0.0f;
#pragma unroll 4
  for (int k4 = 0; k4 < 64; k4++) {
    float4 w = wrow[k4];
    acc += c1[k4 * 4 + 0] * w.x + c1[k4 * 4 + 1] * w.y +
           c1[k4 * 4 + 2] * w.z + c1[k4 * 4 + 3] * w.w;
  }
  actD[(size_t)b * 256 + tid] = fmaxf(acc, 0.0f);
}

// ---------- fc3: [512,256] x [10,256]^T -> d_out [512,10] ----------
__global__ __launch_bounds__(256) void k_fc3(const float* __restrict__ actD,
                                             const float* __restrict__ f3m,
                                             float* __restrict__ out) {
  __shared__ float d1[256];
  int b = blockIdx.x, tid = threadIdx.x;
  d1[tid] = actD[(size_t)b * 256 + tid];
  __syncthreads();
  if (tid < 160) {
    int n = tid >> 4, ksl = tid & 15;
    const float* wr = f3m + (size_t)n * 256 + ksl * 16;
    const float* dd = &d1[ksl * 16];
    float p = 0.0f;
#pragma unroll
    for (int i = 0; i < 16; i++) p += dd[i] * wr[i];
    p += __shfl_xor(p, 8, 16);
    p += __shfl_xor(p, 4, 16);
    p += __shfl_xor(p, 2, 16);
    p += __shfl_xor(p, 1, 16);
    if (ksl == 0) out[(size_t)b * 10 + n] = p;
  }
}

extern "C" void kernel_launch(void* const* d_in, const int* in_sizes, int n_in,
                              void* d_out, int out_size, void* d_ws, size_t ws_size,
                              hipStream_t stream) {
  const float* x  = (const float*)d_in[0];
  const float* w1 = (const float*)d_in[1];
  const float* w2 = (const float*)d_in[2];
  const float* f1 = (const float*)d_in[3];
  const float* f2 = (const float*)d_in[4];
  const float* f3 = (const float*)d_in[5];
  const float* s1 = (const float*)d_in[6];
  const float* s2 = (const float*)d_in[7];
  const float* s3 = (const float*)d_in[8];
  const float* s4 = (const float*)d_in[9];
  const float* s5 = (const float*)d_in[10];

  char* ws = (char*)d_ws;
  u32* hist1  = (u32*)(ws + WS_HIST1);
  u32* hist2  = (u32*)(ws + WS_HIST2);
  u32* coarse = (u32*)(ws + WS_COARSE);
  u32* params = (u32*)(ws + WS_PARAMS);
  u32* ties   = (u32*)(ws + WS_TIES);
  float* wm   = (float*)(ws + WS_WM);
  u32* actA2  = (u32*)(ws + WS_ACTA);
  u16* actBhi = (u16*)(ws + WS_ACTBH);
  u16* actBlo = (u16*)(ws + WS_ACTBL);
  float* part = (float*)(ws + WS_PART);
  float* actC = (float*)(ws + WS_ACTC);
  float* actD = (float*)(ws + WS_ACTD);

  hipMemsetAsync(ws, 0, WS_ZERO_BYTES, stream);

  k_hist1<<<256, 256, 0, stream>>>(s1, s2, s3, s4, s5, hist1);
  k_scan1<<<1, 1024, 0, stream>>>(hist1, params);
  k_hist2<<<256, 256, 0, stream>>>(s1, s2, s3, s4, s5, params, hist2);
  k_coarse<<<1024, 256, 0, stream>>>(hist2, coarse);
  k_scan2<<<1, 1024, 0, stream>>>(hist2, coarse, params);
  k_tie<<<256, 256, 0, stream>>>(s1, s2, s3, s4, s5, params, ties);
  k_cut<<<1, 64, 0, stream>>>(params, ties);
  k_mask<<<1024, 256, 0, stream>>>(s1, s2, s3, s4, s5, w1, w2, f1, f2, f3, params, wm);

  k_conv1<<<512, 256, 0, stream>>>(x, wm + SO1, actA2);
  k_conv2<<<1024, 256, 0, stream>>>(actA2, wm + SO2, actBhi, actBlo);
  k_fc1<<<256, 256, 0, stream>>>(actBhi, actBlo, wm + SO3, part);
  k_fc1fin<<<512, 256, 0, stream>>>(part, actC);
  k_fc2<<<512, 256, 0, stream>>>(actC, wm + SO4, actD);
  k_fc3<<<512, 256, 0, stream>>>(actD, wm + SO5, (float*)d_out);
}

// Round 5
// 678.166 us; speedup vs baseline: 1.2271x; 1.2271x over previous
//
#include <hip/hip_runtime.h>
#include <stdint.h>

typedef unsigned int u32;
typedef unsigned short u16;
typedef short short8 __attribute__((ext_vector_type(8)));
typedef float f32x4 __attribute__((ext_vector_type(4)));

// ---------- problem constants ----------
#define NTOT  4300992
#define JRANK 2150496u

#define SO1 0
#define SO2 1728
#define SO3 38592
#define SO4 4232896
#define SO5 4298432

// params indices
#define P_BIN    0
#define P_JP     1
#define P_TBITS  3
#define P_R      4
#define P_TIECNT 5
#define P_CUT    6

// ---------- workspace layout (bytes) ----------
#define WS_HIST1      0u          // 4096 u32
#define WS_HIST2      16384u      // 524288 u32
#define WS_COARSE     2113536u    // 1024 u32
#define WS_PARAMS     2117632u    // 64 u32
#define WS_ZERO_BYTES 2117888u
#define WS_TIES       2117888u    // 8192 u32
#define WS_WM         4194304u    // NTOT f32 (f1 seg region reused after prep)
#define WS_PART       (WS_WM + 4u*SO3)        // overlay inside wm f1 seg (dead after f1pk)
#define WS_ACTC       (WS_PART + 4194304u)
#define WS_ACTD       (WS_ACTC + 524288u)
#define WS_F1PK       21495808u   // 256*16384 u32
#define WS_WPK        38273024u   // 36864 u32
#define WS_ACTA       41943040u   // 512*1024*64 u32 NHWC packed
#define WS_ACTBH      176160768u  // 512*16384 u16
#define WS_ACTBL      192937984u  // 512*16384 u16  (ends 209715200)

#define TIE_CAP 8192

// ---------- helpers ----------
__device__ __forceinline__ float load_seg(int i, const float* a1, const float* a2,
                                          const float* a3, const float* a4, const float* a5) {
  if (i < SO2) return a1[i];
  if (i < SO3) return a2[i - SO2];
  if (i < SO4) return a3[i - SO3];
  if (i < SO5) return a4[i - SO4];
  return a5[i - SO5];
}

__device__ __forceinline__ u32 absbits(float v) {
  return __float_as_uint(v) & 0x7FFFFFFFu;
}

__device__ __forceinline__ u16 bf16rne(float f) {
  u32 u = __float_as_uint(f);
  u32 r = (u + 0x7FFFu + ((u >> 16) & 1u)) >> 16;
  return (u16)r;
}
__device__ __forceinline__ float bf16tof(u16 h) {
  return __uint_as_float(((u32)h) << 16);
}
__device__ __forceinline__ u32 packsplit(float v) {
  u16 h = bf16rne(v);
  u16 lo = bf16rne(v - bf16tof(h));
  return (u32)h | ((u32)lo << 16);
}

// hi parts of 2 packed u32 -> one u32 (2 bf16); lo parts likewise
#define PERM_HI 0x05040100u
#define PERM_LO 0x07060302u

// ---------- selection: level-1 histogram ----------
__global__ __launch_bounds__(256) void k_hist1(const float* s1, const float* s2, const float* s3,
                                               const float* s4, const float* s5, u32* hist1) {
  __shared__ u32 h[4096];
  for (int i = threadIdx.x; i < 4096; i += 256) h[i] = 0;
  __syncthreads();
  int stride = gridDim.x * blockDim.x;
  for (int i = blockIdx.x * 256 + threadIdx.x; i < NTOT; i += stride) {
    u32 b = absbits(load_seg(i, s1, s2, s3, s4, s5)) >> 19;
    atomicAdd(&h[b], 1u);
  }
  __syncthreads();
  for (int i = threadIdx.x; i < 4096; i += 256) {
    u32 c = h[i];
    if (c) atomicAdd(&hist1[i], c);
  }
}

__global__ __launch_bounds__(1024) void k_scan1(const u32* hist1, u32* params) {
  __shared__ u32 sc[1024];
  int t = threadIdx.x;
  u32 loc[4];
  u32 own = 0;
#pragma unroll
  for (int i = 0; i < 4; i++) { loc[i] = hist1[t * 4 + i]; own += loc[i]; }
  sc[t] = own; __syncthreads();
  for (int off = 1; off < 1024; off <<= 1) {
    u32 add = (t >= off) ? sc[t - off] : 0;
    __syncthreads();
    sc[t] += add;
    __syncthreads();
  }
  u32 incl = sc[t], excl = incl - own;
  if (JRANK >= excl && JRANK < incl) {
    u32 run = excl;
#pragma unroll
    for (int i = 0; i < 4; i++) {
      if (JRANK < run + loc[i]) { params[P_BIN] = (u32)(t * 4 + i); params[P_JP] = JRANK - run; break; }
      run += loc[i];
    }
  }
}

__global__ __launch_bounds__(256) void k_hist2(const float* s1, const float* s2, const float* s3,
                                               const float* s4, const float* s5,
                                               const u32* params, u32* hist2) {
  u32 bsel = params[P_BIN];
  int stride = gridDim.x * blockDim.x;
  for (int i = blockIdx.x * 256 + threadIdx.x; i < NTOT; i += stride) {
    u32 b = absbits(load_seg(i, s1, s2, s3, s4, s5));
    if ((b >> 19) == bsel) atomicAdd(&hist2[b & 0x7FFFFu], 1u);
  }
}

__global__ __launch_bounds__(256) void k_coarse(const u32* hist2, u32* coarse) {
  __shared__ u32 red[256];
  int blk = blockIdx.x;
  u32 s = hist2[blk * 512 + threadIdx.x] + hist2[blk * 512 + 256 + threadIdx.x];
  red[threadIdx.x] = s; __syncthreads();
  for (int off = 128; off > 0; off >>= 1) {
    if (threadIdx.x < off) red[threadIdx.x] += red[threadIdx.x + off];
    __syncthreads();
  }
  if (threadIdx.x == 0) coarse[blk] = red[0];
}

__global__ __launch_bounds__(1024) void k_scan2(const u32* hist2, const u32* coarse, u32* params) {
  __shared__ u32 sc[1024];
  __shared__ u32 s_seg, s_base;
  int t = threadIdx.x;
  u32 jp = params[P_JP];
  u32 own = coarse[t];
  sc[t] = own; __syncthreads();
  for (int off = 1; off < 1024; off <<= 1) {
    u32 add = (t >= off) ? sc[t - off] : 0;
    __syncthreads();
    sc[t] += add;
    __syncthreads();
  }
  u32 incl = sc[t], excl = incl - own;
  if (jp >= excl && jp < incl) { s_seg = (u32)t; s_base = excl; }
  __syncthreads();
  u32 seg = s_seg, base = s_base, tgt = jp - base;
  u32 own2 = (t < 512) ? hist2[seg * 512 + t] : 0;
  __syncthreads();
  sc[t] = own2; __syncthreads();
  for (int off = 1; off < 1024; off <<= 1) {
    u32 add = (t >= off) ? sc[t - off] : 0;
    __syncthreads();
    sc[t] += add;
    __syncthreads();
  }
  u32 incl2 = sc[t], excl2 = incl2 - own2;
  if (t < 512 && tgt >= excl2 && tgt < incl2) {
    u32 b = params[P_BIN];
    params[P_TBITS] = (b << 19) | (seg * 512 + (u32)t);
    params[P_R] = tgt - excl2;
  }
}

__global__ __launch_bounds__(256) void k_tie(const float* s1, const float* s2, const float* s3,
                                             const float* s4, const float* s5,
                                             u32* params, u32* ties) {
  u32 tb = params[P_TBITS];
  int stride = gridDim.x * blockDim.x;
  for (int i = blockIdx.x * 256 + threadIdx.x; i < NTOT; i += stride) {
    if (absbits(load_seg(i, s1, s2, s3, s4, s5)) == tb) {
      u32 pos = atomicAdd(&params[P_TIECNT], 1u);
      if (pos < TIE_CAP) ties[pos] = (u32)i;
    }
  }
}

__global__ void k_cut(u32* params, const u32* ties) {
  if (threadIdx.x != 0 || blockIdx.x != 0) return;
  u32 m = params[P_TIECNT]; if (m > TIE_CAP) m = TIE_CAP;
  u32 r = params[P_R];
  u32 cut;
  if (r == 0) cut = 0u;
  else if (r >= m) cut = 0xFFFFFFFFu;
  else {
    long long last = -1;
    for (u32 s = 0; s < r; s++) {
      u32 cur = 0xFFFFFFFFu;
      for (u32 k = 0; k < m; k++) {
        u32 v = ties[k];
        if ((long long)v > last && v < cur) cur = v;
      }
      last = (long long)cur;
    }
    cut = (u32)(last + 1);
  }
  params[P_CUT] = cut;
}

// ---------- mask: wm[i] = keep ? w[i] : 0 ; f1 seg additionally packed u32 ----------
__global__ __launch_bounds__(256) void k_mask(const float* s1, const float* s2, const float* s3,
                                              const float* s4, const float* s5,
                                              const float* w1, const float* w2, const float* w3,
                                              const float* w4, const float* w5,
                                              const u32* params, float* wm, u32* f1pk) {
  u32 tb = params[P_TBITS];
  u32 cut = params[P_CUT];
  int stride = gridDim.x * blockDim.x;
  for (int i = blockIdx.x * 256 + threadIdx.x; i < NTOT; i += stride) {
    u32 b = absbits(load_seg(i, s1, s2, s3, s4, s5));
    bool keep = (b > tb) || (b == tb && (u32)i >= cut);
    float v = keep ? load_seg(i, w1, w2, w3, w4, w5) : 0.0f;
    if (i >= SO3 && i < SO4) {
      f1pk[i - SO3] = packsplit(v);
    } else {
      wm[i] = v;
    }
  }
}

// ---------- weight prep for conv2: frag-ordered packed u32 ----------
// wpk[((s*4+tau)*2+c)*512 + l*8 + j] = packed w2m[oc=tau*16+(l&15)][ic=c*32+(l>>4)*8+j][s]
__global__ __launch_bounds__(256) void k_wprep(const float* wm2, u32* wpk) {
  int idx = blockIdx.x * 256 + threadIdx.x;
  if (idx >= 36864) return;
  int j = idx & 7, l = (idx >> 3) & 63, c = (idx >> 9) & 1, tau = (idx >> 10) & 3, s = idx >> 12;
  int ic = c * 32 + (l >> 4) * 8 + j;
  int oc = tau * 16 + (l & 15);
  wpk[idx] = packsplit(wm2[oc * 576 + ic * 9 + s]);
}

// ---------- conv1: [512,3,32,32] -> relu -> NHWC packed u32 [img][y][x][ic] ----------
// grid 2048 = 512 img x 4 ybands(8 rows). thread (p=tid>>4: row/colhalf, q=tid&15: ic-quad)
__global__ __launch_bounds__(256, 2) void k_conv1(const float* __restrict__ x,
                                                  const float* __restrict__ wm1,
                                                  u32* __restrict__ actA) {
  __shared__ float xsm[3 * 10 * 36];   // [c][yy 0..9][xx 0..35]
  __shared__ float wsm[64 * 29];       // [oc][k27] pad 29
  int blk = blockIdx.x;
  int img = blk >> 2, yb = blk & 3, y0 = yb * 8;
  int tid = threadIdx.x;
  for (int i = tid; i < 1728; i += 256) {
    int oc = i / 27, k = i - oc * 27;
    wsm[oc * 29 + k] = wm1[i];
  }
  for (int i = tid; i < 1020; i += 256) {
    int c = i / 340, r = i - c * 340;
    int yy = r / 34, xx = r - yy * 34;
    int y = y0 - 1 + yy, xg = xx - 1;
    float v = 0.0f;
    if (y >= 0 && y < 32 && xg >= 0 && xg < 32)
      v = x[(size_t)img * 3072 + c * 1024 + y * 32 + xg];
    xsm[c * 360 + yy * 36 + xx] = v;
  }
  __syncthreads();
  int q = tid & 15, p = tid >> 4;
  int row = p >> 1, col0 = (p & 1) * 16;   // row 0..7 within band, 16 cols
  float acc[4][16];
#pragma unroll
  for (int o = 0; o < 4; o++)
#pragma unroll
    for (int px = 0; px < 16; px++) acc[o][px] = 0.0f;
#pragma unroll
  for (int c = 0; c < 3; c++) {
#pragma unroll
    for (int ky = 0; ky < 3; ky++) {
      float in[18];
#pragma unroll
      for (int d = 0; d < 18; d++) in[d] = xsm[c * 360 + (row + ky) * 36 + col0 + d];
#pragma unroll
      for (int kx = 0; kx < 3; kx++) {
#pragma unroll
        for (int o = 0; o < 4; o++) {
          float wv = wsm[(q * 4 + o) * 29 + c * 9 + ky * 3 + kx];  // LDS broadcast, 2-way alias
#pragma unroll
          for (int px = 0; px < 16; px++) acc[o][px] += wv * in[px + kx];
        }
      }
    }
  }
  // store: per px, 4 ic contiguous -> uint4
  int y = y0 + row;
#pragma unroll
  for (int px = 0; px < 16; px++) {
    u32 w4[4];
#pragma unroll
    for (int o = 0; o < 4; o++) w4[o] = packsplit(fmaxf(acc[o][px], 0.0f));
    *(uint4*)(actA + ((size_t)img * 1024 + y * 32 + col0 + px) * 64 + q * 4) =
        make_uint4(w4[0], w4[1], w4[2], w4[3]);
  }
}

// ---------- conv2 (MFMA bf16 split-3, x LDS only, w direct-global) + relu + pool ----------
// grid 512 (1 img/block). 4 waves = (mh: row-pair, nh: 32-oc half). band = 4 out rows.
__global__ __launch_bounds__(256, 2) void k_conv2(const u32* __restrict__ actA,
                                                  const u32* __restrict__ wpk,
                                                  u16* __restrict__ actBhi,
                                                  u16* __restrict__ actBlo) {
  __shared__ u32 xs[204 * 68];   // [6 rows x 34 x][64 ic + 4 pad] = 55488 B
  int img = blockIdx.x;
  int tid = threadIdx.x;
  int l = tid & 63, wv = tid >> 6;
  int mh = wv & 1, nh = wv >> 1;
  int ln15 = l & 15, lh = l >> 4;
  const u32* src = actA + (size_t)img * 65536;
  const f32x4 vzero = {0.f, 0.f, 0.f, 0.f};

  for (int band = 0; band < 8; band++) {
    int r0 = band * 4;
    __syncthreads();
    for (int i = tid; i < 3264; i += 256) {
      int row = i >> 4, q = i & 15;
      int ry = row / 34, rx = row - ry * 34;
      int y = r0 - 1 + ry, xg = rx - 1;
      uint4 v = make_uint4(0, 0, 0, 0);
      if (y >= 0 && y < 32 && xg >= 0 && xg < 32)
        v = *(const uint4*)(src + (y * 32 + xg) * 64 + q * 4);
      *(uint4*)&xs[row * 68 + q * 4] = v;
    }
    __syncthreads();

    f32x4 acc[4][2];
#pragma unroll
    for (int mi = 0; mi < 4; mi++)
#pragma unroll
      for (int t = 0; t < 2; t++) acc[mi][t] = vzero;

#pragma unroll
    for (int ky = 0; ky < 3; ky++) {
#pragma unroll
      for (int kx = 0; kx < 3; kx++) {
        int s = ky * 3 + kx;
#pragma unroll
        for (int c = 0; c < 2; c++) {
          // B frags for 2 oc-tiles, direct from global (L2-hot, 147 KB total)
          const u32* wb = wpk + ((s * 4 + nh * 2) * 2 + c) * 512 + l * 8;
          uint4 br0 = *(const uint4*)wb;
          uint4 br1 = *(const uint4*)(wb + 4);
          uint4 br2 = *(const uint4*)(wb + 1024);
          uint4 br3 = *(const uint4*)(wb + 1028);
          union { u32 u[4]; short8 s8; } bh0, bl0, bh1, bl1;
          bh0.u[0] = __builtin_amdgcn_perm(br0.y, br0.x, PERM_HI);
          bh0.u[1] = __builtin_amdgcn_perm(br0.w, br0.z, PERM_HI);
          bh0.u[2] = __builtin_amdgcn_perm(br1.y, br1.x, PERM_HI);
          bh0.u[3] = __builtin_amdgcn_perm(br1.w, br1.z, PERM_HI);
          bl0.u[0] = __builtin_amdgcn_perm(br0.y, br0.x, PERM_LO);
          bl0.u[1] = __builtin_amdgcn_perm(br0.w, br0.z, PERM_LO);
          bl0.u[2] = __builtin_amdgcn_perm(br1.y, br1.x, PERM_LO);
          bl0.u[3] = __builtin_amdgcn_perm(br1.w, br1.z, PERM_LO);
          bh1.u[0] = __builtin_amdgcn_perm(br2.y, br2.x, PERM_HI);
          bh1.u[1] = __builtin_amdgcn_perm(br2.w, br2.z, PERM_HI);
          bh1.u[2] = __builtin_amdgcn_perm(br3.y, br3.x, PERM_HI);
          bh1.u[3] = __builtin_amdgcn_perm(br3.w, br3.z, PERM_HI);
          bl1.u[0] = __builtin_amdgcn_perm(br2.y, br2.x, PERM_LO);
          bl1.u[1] = __builtin_amdgcn_perm(br2.w, br2.z, PERM_LO);
          bl1.u[2] = __builtin_amdgcn_perm(br3.y, br3.x, PERM_LO);
          bl1.u[3] = __builtin_amdgcn_perm(br3.w, br3.z, PERM_LO);
#pragma unroll
          for (int mi = 0; mi < 4; mi++) {
            int row = (2 * mh + (mi >> 1) + ky) * 34 + (mi & 1) * 16 + ln15 + kx;
            const u32* xa = &xs[row * 68 + c * 32 + lh * 8];
            uint4 ar0 = *(const uint4*)xa;
            uint4 ar1 = *(const uint4*)(xa + 4);
            union { u32 u[4]; short8 s8; } ah, al;
            ah.u[0] = __builtin_amdgcn_perm(ar0.y, ar0.x, PERM_HI);
            ah.u[1] = __builtin_amdgcn_perm(ar0.w, ar0.z, PERM_HI);
            ah.u[2] = __builtin_amdgcn_perm(ar1.y, ar1.x, PERM_HI);
            ah.u[3] = __builtin_amdgcn_perm(ar1.w, ar1.z, PERM_HI);
            al.u[0] = __builtin_amdgcn_perm(ar0.y, ar0.x, PERM_LO);
            al.u[1] = __builtin_amdgcn_perm(ar0.w, ar0.z, PERM_LO);
            al.u[2] = __builtin_amdgcn_perm(ar1.y, ar1.x, PERM_LO);
            al.u[3] = __builtin_amdgcn_perm(ar1.w, ar1.z, PERM_LO);
            acc[mi][0] = __builtin_amdgcn_mfma_f32_16x16x32_bf16(ah.s8, bh0.s8, acc[mi][0], 0, 0, 0);
            acc[mi][0] = __builtin_amdgcn_mfma_f32_16x16x32_bf16(ah.s8, bl0.s8, acc[mi][0], 0, 0, 0);
            acc[mi][0] = __builtin_amdgcn_mfma_f32_16x16x32_bf16(al.s8, bh0.s8, acc[mi][0], 0, 0, 0);
            acc[mi][1] = __builtin_amdgcn_mfma_f32_16x16x32_bf16(ah.s8, bh1.s8, acc[mi][1], 0, 0, 0);
            acc[mi][1] = __builtin_amdgcn_mfma_f32_16x16x32_bf16(ah.s8, bl1.s8, acc[mi][1], 0, 0, 0);
            acc[mi][1] = __builtin_amdgcn_mfma_f32_16x16x32_bf16(al.s8, bh1.s8, acc[mi][1], 0, 0, 0);
          }
        }
      }
    }

    // epilogue: 2x2 maxpool + relu + split store. pooled row py = band*2+mh
    int py = band * 2 + mh;
#pragma unroll
    for (int tau = 0; tau < 2; tau++) {
      int oc = nh * 32 + tau * 16 + ln15;
      size_t ob = ((size_t)img * 64 + oc) * 256 + py * 16;
#pragma unroll
      for (int xh2 = 0; xh2 < 2; xh2++) {
#pragma unroll
        for (int u = 0; u < 2; u++) {
          float a = fmaxf(fmaxf(acc[xh2][tau][2 * u], acc[xh2][tau][2 * u + 1]),
                          fmaxf(acc[xh2 + 2][tau][2 * u], acc[xh2 + 2][tau][2 * u + 1]));
          a = fmaxf(a, 0.0f);
          u16 h = bf16rne(a);
          u16 lo = bf16rne(a - bf16tof(h));
          int pxo = xh2 * 8 + lh * 2 + u;
          actBhi[ob + pxo] = h;
          actBlo[ob + pxo] = lo;
        }
      }
    }
  }
}

// ---------- fc1 (MFMA split-3): [512,16384] x [256,16384]^T, K-split 8 ----------
// grid 256 = 8ks x 8m x 4n. 512 thr (8 waves = mh2 x nh4). K-step 64.
__global__ __launch_bounds__(512, 1) void k_fc1(const u16* __restrict__ Ahi,
                                                const u16* __restrict__ Alo,
                                                const u32* __restrict__ f1pk,
                                                float* __restrict__ part) {
  __shared__ u16 Ash[64 * 72];
  __shared__ u16 Asl[64 * 72];
  __shared__ u32 Bs[64 * 68];
  int blk = blockIdx.x;
  int ks = blk >> 5, ms = (blk >> 2) & 7, ns = blk & 3;
  int m0 = ms * 64, n0 = ns * 64, kbase = ks * 2048;
  int tid = threadIdx.x;
  int l = tid & 63, wv = tid >> 6;
  int mh = wv & 1, nh = wv >> 1;
  int ln15 = l & 15, lh = l >> 4;
  const f32x4 vzero = {0.f, 0.f, 0.f, 0.f};
  f32x4 acc[2];
  acc[0] = vzero; acc[1] = vzero;

  for (int step = 0; step < 32; step++) {
    int k0 = kbase + step * 64;
    __syncthreads();
    {
      int m = tid >> 3, kq = tid & 7;
      size_t ga = (size_t)(m0 + m) * 16384 + k0 + kq * 8;
      *(uint4*)&Ash[m * 72 + kq * 8] = *(const uint4*)(Ahi + ga);
      *(uint4*)&Asl[m * 72 + kq * 8] = *(const uint4*)(Alo + ga);
    }
#pragma unroll
    for (int rep = 0; rep < 2; rep++) {
      int i = tid + rep * 512;
      int n = i >> 4, kq = i & 15;
      *(uint4*)&Bs[n * 68 + kq * 4] = *(const uint4*)(f1pk + (size_t)(n0 + n) * 16384 + k0 + kq * 4);
    }
    __syncthreads();
#pragma unroll
    for (int c = 0; c < 2; c++) {
      const u32* bb = &Bs[(nh * 16 + ln15) * 68 + c * 32 + lh * 8];
      uint4 br0 = *(const uint4*)bb;
      uint4 br1 = *(const uint4*)(bb + 4);
      union { u32 u[4]; short8 s8; } bh, bl;
      bh.u[0] = __builtin_amdgcn_perm(br0.y, br0.x, PERM_HI);
      bh.u[1] = __builtin_amdgcn_perm(br0.w, br0.z, PERM_HI);
      bh.u[2] = __builtin_amdgcn_perm(br1.y, br1.x, PERM_HI);
      bh.u[3] = __builtin_amdgcn_perm(br1.w, br1.z, PERM_HI);
      bl.u[0] = __builtin_amdgcn_perm(br0.y, br0.x, PERM_LO);
      bl.u[1] = __builtin_amdgcn_perm(br0.w, br0.z, PERM_LO);
      bl.u[2] = __builtin_amdgcn_perm(br1.y, br1.x, PERM_LO);
      bl.u[3] = __builtin_amdgcn_perm(br1.w, br1.z, PERM_LO);
#pragma unroll
      for (int mt = 0; mt < 2; mt++) {
        int ra = ((mh * 2 + mt) * 16 + ln15) * 72 + c * 32 + lh * 8;
        union { uint4 q; short8 s8; } ah, al;
        ah.q = *(const uint4*)&Ash[ra];
        al.q = *(const uint4*)&Asl[ra];
        acc[mt] = __builtin_amdgcn_mfma_f32_16x16x32_bf16(ah.s8, bh.s8, acc[mt], 0, 0, 0);
        acc[mt] = __builtin_amdgcn_mfma_f32_16x16x32_bf16(ah.s8, bl.s8, acc[mt], 0, 0, 0);
        acc[mt] = __builtin_amdgcn_mfma_f32_16x16x32_bf16(al.s8, bh.s8, acc[mt], 0, 0, 0);
      }
    }
  }
  float* dst = part + (size_t)ks * 131072;
#pragma unroll
  for (int mt = 0; mt < 2; mt++) {
#pragma unroll
    for (int g = 0; g < 4; g++) {
      int m = m0 + (mh * 2 + mt) * 16 + lh * 4 + g;
      dst[(size_t)m * 256 + n0 + nh * 16 + ln15] = acc[mt][g];
    }
  }
}

// ---------- fc1 finalize ----------
__global__ __launch_bounds__(256) void k_fc1fin(const float* __restrict__ part,
                                                float* __restrict__ actC) {
  int i = blockIdx.x * 256 + threadIdx.x;
  float s = 0.0f;
#pragma unroll
  for (int ks = 0; ks < 8; ks++) s += part[(size_t)ks * 131072 + i];
  actC[i] = fmaxf(s, 0.0f);
}

// ---------- fc2 ----------
__global__ __launch_bounds__(256) void k_fc2(const float* __restrict__ actC,
                                             const float* __restrict__ f2m,
                                             float* __restrict__ actD) {
  __shared__ float c1[256];
  int b = blockIdx.x, tid = threadIdx.x;
  c1[tid] = actC[(size_t)b * 256 + tid];
  __syncthreads();
  const float4* wrow = (const float4*)(f2m + (size_t)tid * 256);
  float acc = 0.0f;
#pragma unroll 4
  for (int k4 = 0; k4 < 64; k4++) {
    float4 w = wrow[k4];
    acc += c1[k4 * 4 + 0] * w.x + c1[k4 * 4 + 1] * w.y +
           c1[k4 * 4 + 2] * w.z + c1[k4 * 4 + 3] * w.w;
  }
  actD[(size_t)b * 256 + tid] = fmaxf(acc, 0.0f);
}

// ---------- fc3 ----------
__global__ __launch_bounds__(256) void k_fc3(const float* __restrict__ actD,
                                             const float* __restrict__ f3m,
                                             float* __restrict__ out) {
  __shared__ float d1[256];
  int b = blockIdx.x, tid = threadIdx.x;
  d1[tid] = actD[(size_t)b * 256 + tid];
  __syncthreads();
  if (tid < 160) {
    int n = tid >> 4, ksl = tid & 15;
    const float* wr = f3m + (size_t)n * 256 + ksl * 16;
    const float* dd = &d1[ksl * 16];
    float p = 0.0f;
#pragma unroll
    for (int i = 0; i < 16; i++) p += dd[i] * wr[i];
    p += __shfl_xor(p, 8, 16);
    p += __shfl_xor(p, 4, 16);
    p += __shfl_xor(p, 2, 16);
    p += __shfl_xor(p, 1, 16);
    if (ksl == 0) out[(size_t)b * 10 + n] = p;
  }
}

extern "C" void kernel_launch(void* const* d_in, const int* in_sizes, int n_in,
                              void* d_out, int out_size, void* d_ws, size_t ws_size,
                              hipStream_t stream) {
  const float* x  = (const float*)d_in[0];
  const float* w1 = (const float*)d_in[1];
  const float* w2 = (const float*)d_in[2];
  const float* f1 = (const float*)d_in[3];
  const float* f2 = (const float*)d_in[4];
  const float* f3 = (const float*)d_in[5];
  const float* s1 = (const float*)d_in[6];
  const float* s2 = (const float*)d_in[7];
  const float* s3 = (const float*)d_in[8];
  const float* s4 = (const float*)d_in[9];
  const float* s5 = (const float*)d_in[10];

  char* ws = (char*)d_ws;
  u32* hist1  = (u32*)(ws + WS_HIST1);
  u32* hist2  = (u32*)(ws + WS_HIST2);
  u32* coarse = (u32*)(ws + WS_COARSE);
  u32* params = (u32*)(ws + WS_PARAMS);
  u32* ties   = (u32*)(ws + WS_TIES);
  float* wm   = (float*)(ws + WS_WM);
  u32* f1pk   = (u32*)(ws + WS_F1PK);
  u32* wpk    = (u32*)(ws + WS_WPK);
  u32* actA   = (u32*)(ws + WS_ACTA);
  u16* actBhi = (u16*)(ws + WS_ACTBH);
  u16* actBlo = (u16*)(ws + WS_ACTBL);
  float* part = (float*)(ws + WS_PART);
  float* actC = (float*)(ws + WS_ACTC);
  float* actD = (float*)(ws + WS_ACTD);

  hipMemsetAsync(ws, 0, WS_ZERO_BYTES, stream);

  k_hist1<<<256, 256, 0, stream>>>(s1, s2, s3, s4, s5, hist1);
  k_scan1<<<1, 1024, 0, stream>>>(hist1, params);
  k_hist2<<<256, 256, 0, stream>>>(s1, s2, s3, s4, s5, params, hist2);
  k_coarse<<<1024, 256, 0, stream>>>(hist2, coarse);
  k_scan2<<<1, 1024, 0, stream>>>(hist2, coarse, params);
  k_tie<<<256, 256, 0, stream>>>(s1, s2, s3, s4, s5, params, ties);
  k_cut<<<1, 64, 0, stream>>>(params, ties);
  k_mask<<<1024, 256, 0, stream>>>(s1, s2, s3, s4, s5, w1, w2, f1, f2, f3, params, wm, f1pk);

  k_wprep<<<144, 256, 0, stream>>>(wm + SO2, wpk);
  k_conv1<<<2048, 256, 0, stream>>>(x, wm + SO1, actA);
  k_conv2<<<512, 256, 0, stream>>>(actA, wpk, actBhi, actBlo);
  k_fc1<<<256, 512, 0, stream>>>(actBhi, actBlo, f1pk, part);
  k_fc1fin<<<512, 256, 0, stream>>>(part, actC);
  k_fc2<<<512, 256, 0, stream>>>(actC, wm + SO4, actD);
  k_fc3<<<512, 256, 0, stream>>>(actD, wm + SO5, (float*)d_out);
}